// Round 1
// 913.000 us; speedup vs baseline: 1.3117x; 1.3117x over previous
//
#include <hip/hip_runtime.h>

typedef unsigned short ushort_t;
typedef __attribute__((ext_vector_type(8))) short short8;
typedef __attribute__((ext_vector_type(8))) unsigned short ushort8;
typedef __attribute__((ext_vector_type(4))) unsigned short ushort4v;
typedef __attribute__((ext_vector_type(4))) float floatx4;

static __device__ __forceinline__ ushort_t f2b(float f) {
    unsigned int x;
    __builtin_memcpy(&x, &f, 4);
    x += 0x7fffu + ((x >> 16) & 1u);   // round-to-nearest-even
    return (ushort_t)(x >> 16);
}
static __device__ __forceinline__ float b2f(ushort_t u) {
    unsigned int x = ((unsigned int)u) << 16;
    float f;
    __builtin_memcpy(&f, &x, 4);
    return f;
}

// load 8 consecutive elements as bf16x8 (converting if source is f32)
static __device__ __forceinline__ ushort8 ld8bf(const float* p) {
    const floatx4* q = (const floatx4*)p;
    floatx4 a = q[0], b = q[1];
    ushort8 r;
    r[0] = f2b(a[0]); r[1] = f2b(a[1]); r[2] = f2b(a[2]); r[3] = f2b(a[3]);
    r[4] = f2b(b[0]); r[5] = f2b(b[1]); r[6] = f2b(b[2]); r[7] = f2b(b[3]);
    return r;
}
static __device__ __forceinline__ ushort8 ld8bf(const ushort_t* p) {
    return *(const ushort8*)p;
}
static __device__ __forceinline__ void stc(float* C, long long idx, float v) { C[idx] = v; }
static __device__ __forceinline__ void stc(ushort_t* C, long long idx, float v) { C[idx] = f2b(v); }

// ---------------------------------------------------------------------------
// NT GEMM: C[m,n] = alpha * (sum_k A[m,k]*B[n,k]) + bias[n or m]
// A:(M,K) lda, B:(N,K) ldb (both f32 or bf16), C:(M,N) ldc (f32 or bf16).
// MFMA in bf16, f32 accumulate. Batched via blockIdx.z.
// Block 256 thr = 4 waves; tile 128x128, BK=32; wave = 64x64 (4x4 MFMA tiles).
// BROW=true -> bias indexed by output ROW (used for the transposed V proj).
// ---------------------------------------------------------------------------
template <typename TA, typename TB, typename TC, bool BROW>
__global__ __launch_bounds__(256) void gemm_nt_kernel(
    const TA* __restrict__ A, const TB* __restrict__ Bm,
    const float* __restrict__ bias, TC* __restrict__ C,
    int K, int lda, int ldb, int ldc,
    int innerCnt, long long sAo, long long sAi, long long sBo, long long sBi,
    long long sCo, long long sCi,
    const float* __restrict__ alphaPtr)
{
    __shared__ __align__(16) ushort_t sA[128][40];  // +8 pad: 2-way alias only (free)
    __shared__ __align__(16) ushort_t sB[128][40];

    const int z = blockIdx.z;
    const int zo = z / innerCnt, zi = z % innerCnt;
    A  += (long long)zo * sAo + (long long)zi * sAi;
    Bm += (long long)zo * sBo + (long long)zi * sBi;
    C  += (long long)zo * sCo + (long long)zi * sCi;

    const int m0 = blockIdx.y * 128;
    const int n0 = blockIdx.x * 128;
    const int t = threadIdx.x;
    const int lane = t & 63;
    const int wave = t >> 6;
    const int wm = (wave >> 1) * 64;
    const int wn = (wave & 1) * 64;
    const int lr = lane & 15;
    const int lk = (lane >> 4) * 8;
    const int lq = (lane >> 4) * 4;

    floatx4 acc[4][4];
    #pragma unroll
    for (int i = 0; i < 4; ++i)
        #pragma unroll
        for (int j = 0; j < 4; ++j)
            acc[i][j] = (floatx4){0.f, 0.f, 0.f, 0.f};

    const int r0 = t >> 2;          // staging row 0..63
    const int c0 = (t & 3) * 8;     // staging col {0,8,16,24}

    for (int k0 = 0; k0 < K; k0 += 32) {
        ushort8 va0 = ld8bf(A  + (long long)(m0 + r0)      * lda + (k0 + c0));
        ushort8 va1 = ld8bf(A  + (long long)(m0 + 64 + r0) * lda + (k0 + c0));
        ushort8 vb0 = ld8bf(Bm + (long long)(n0 + r0)      * ldb + (k0 + c0));
        ushort8 vb1 = ld8bf(Bm + (long long)(n0 + 64 + r0) * ldb + (k0 + c0));
        *(ushort8*)(&sA[r0][c0])      = va0;
        *(ushort8*)(&sA[64 + r0][c0]) = va1;
        *(ushort8*)(&sB[r0][c0])      = vb0;
        *(ushort8*)(&sB[64 + r0][c0]) = vb1;
        __syncthreads();

        short8 af[4], bf[4];
        #pragma unroll
        for (int mi = 0; mi < 4; ++mi)
            af[mi] = *(const short8*)(&sA[wm + mi * 16 + lr][lk]);
        #pragma unroll
        for (int ni = 0; ni < 4; ++ni)
            bf[ni] = *(const short8*)(&sB[wn + ni * 16 + lr][lk]);
        #pragma unroll
        for (int mi = 0; mi < 4; ++mi)
            #pragma unroll
            for (int ni = 0; ni < 4; ++ni)
                acc[mi][ni] = __builtin_amdgcn_mfma_f32_16x16x32_bf16(
                    af[mi], bf[ni], acc[mi][ni], 0, 0, 0);
        __syncthreads();
    }

    const float alpha = alphaPtr ? *alphaPtr : 1.0f;

    #pragma unroll
    for (int mi = 0; mi < 4; ++mi) {
        #pragma unroll
        for (int ni = 0; ni < 4; ++ni) {
            const int col = n0 + wn + ni * 16 + lr;
            const float bcol = (!BROW && bias) ? bias[col] : 0.0f;
            #pragma unroll
            for (int r = 0; r < 4; ++r) {
                const int row = m0 + wm + mi * 16 + lq + r;
                const float bb = BROW ? (bias ? bias[row] : 0.0f) : bcol;
                stc(C, (long long)row * ldc + col, acc[mi][ni][r] * alpha + bb);
            }
        }
    }
}

// ---------------------------------------------------------------------------
// Fused attention for one head: scores -> softmax -> attn write -> P@V.
// Two passes over K with score recompute (scores are 17 GFLOP; re-reading
// them from HBM would be 1.07 GB).
// Q tile = 64 rows, K tile = 128. 4 waves, each owns 16 Q-rows x all cols.
// Pass 1: online row-max m and row-sum l (no stores).
// Pass 2: recompute S (bitwise identical), p = exp(s-m)/l, write f32 attn
//         once, p->bf16 into LDS, O += P·V with pre-transposed Vt in LDS.
// LDS = 62.4 KB -> 2 blocks/CU. Grid = (32 q-tiles, 32 bh).
// ---------------------------------------------------------------------------
__global__ __launch_bounds__(256) void fused_attn_kernel(
    const ushort_t* __restrict__ Qb, const ushort_t* __restrict__ Kb,
    const ushort_t* __restrict__ Vt, float* __restrict__ attn,
    ushort_t* __restrict__ Cx, const float* __restrict__ temp)
{
    __shared__ __align__(16) ushort_t sQ[64][72];    //  9.2 KB
    __shared__ __align__(16) ushort_t sK[128][72];   // 18.4 KB
    __shared__ __align__(16) ushort_t sVt[64][136];  // 17.4 KB  [d][k]
    __shared__ __align__(16) ushort_t sP[64][136];   // 17.4 KB  [q][k]

    const int bh = blockIdx.y;               // b*16 + h
    const int b  = bh >> 4;
    const int h  = bh & 15;
    const int q0 = blockIdx.x * 64;
    const int t = threadIdx.x;
    const int lane = t & 63;
    const int w = t >> 6;                    // wave owns q-rows w*16..w*16+15
    const int lr = lane & 15;
    const int lk = (lane >> 4) * 8;
    const int lq = (lane >> 4) * 4;
    const float tscale = *temp;

    const long long qkBase = ((long long)b * 2048) * 1024 + h * 64; // Qb/Kb/Cx head base
    const long long vtBase = (long long)bh * 131072;                // Vt[bh][64][2048]
    float* attnB = attn + ((long long)bh * 2048 + q0) * 2048;

    // ---- stage Q tile (64x64), once ----
    {
        const int row = t >> 2, c0 = (t & 3) * 16;
        const ushort_t* src = Qb + qkBase + (long long)(q0 + row) * 1024 + c0;
        *(ushort8*)(&sQ[row][c0])     = *(const ushort8*)(src);
        *(ushort8*)(&sQ[row][c0 + 8]) = *(const ushort8*)(src + 8);
    }

    const int krow = t >> 1, kc0 = (t & 1) * 32;   // sK staging: 128 rows x 64
    const int vd   = t >> 2, vc0 = (t & 3) * 32;   // sVt staging: 64 rows x 128

    float m[4], l[4];
    #pragma unroll
    for (int r = 0; r < 4; ++r) { m[r] = -1e30f; l[r] = 0.f; }

    // ---------------- pass 1: row max & sum ----------------
    for (int kt = 0; kt < 16; ++kt) {
        const int k0 = kt * 128;
        __syncthreads();   // previous iter's readers done before restage
        {
            const ushort_t* src = Kb + qkBase + (long long)(k0 + krow) * 1024 + kc0;
            #pragma unroll
            for (int j = 0; j < 4; ++j)
                *(ushort8*)(&sK[krow][kc0 + j * 8]) = *(const ushort8*)(src + j * 8);
        }
        __syncthreads();

        floatx4 s[8];
        #pragma unroll
        for (int ni = 0; ni < 8; ++ni) s[ni] = (floatx4){0.f, 0.f, 0.f, 0.f};
        #pragma unroll
        for (int ks = 0; ks < 2; ++ks) {
            short8 aq = *(const short8*)(&sQ[w * 16 + lr][ks * 32 + lk]);
            #pragma unroll
            for (int ni = 0; ni < 8; ++ni) {
                short8 bk = *(const short8*)(&sK[ni * 16 + lr][ks * 32 + lk]);
                s[ni] = __builtin_amdgcn_mfma_f32_16x16x32_bf16(aq, bk, s[ni], 0, 0, 0);
            }
        }
        #pragma unroll
        for (int ni = 0; ni < 8; ++ni) s[ni] *= tscale;

        #pragma unroll
        for (int r = 0; r < 4; ++r) {
            float tm = -1e30f;
            #pragma unroll
            for (int ni = 0; ni < 8; ++ni) tm = fmaxf(tm, s[ni][r]);
            #pragma unroll
            for (int o = 8; o > 0; o >>= 1) tm = fmaxf(tm, __shfl_xor(tm, o, 64));
            const float nm = fmaxf(m[r], tm);
            float ts = 0.f;
            #pragma unroll
            for (int ni = 0; ni < 8; ++ni) ts += __expf(s[ni][r] - nm);
            #pragma unroll
            for (int o = 8; o > 0; o >>= 1) ts += __shfl_xor(ts, o, 64);
            l[r] = l[r] * __expf(m[r] - nm) + ts;
            m[r] = nm;
        }
    }

    float invl[4];
    #pragma unroll
    for (int r = 0; r < 4; ++r) invl[r] = 1.0f / l[r];

    floatx4 o_acc[4];
    #pragma unroll
    for (int nj = 0; nj < 4; ++nj) o_acc[nj] = (floatx4){0.f, 0.f, 0.f, 0.f};

    // ---------------- pass 2: normalize, write attn, P@V ----------------
    for (int kt = 0; kt < 16; ++kt) {
        const int k0 = kt * 128;
        __syncthreads();   // previous iter's PV reads done before restage
        {
            const ushort_t* src = Kb + qkBase + (long long)(k0 + krow) * 1024 + kc0;
            #pragma unroll
            for (int j = 0; j < 4; ++j)
                *(ushort8*)(&sK[krow][kc0 + j * 8]) = *(const ushort8*)(src + j * 8);
            const ushort_t* vsrc = Vt + vtBase + (long long)vd * 2048 + k0 + vc0;
            #pragma unroll
            for (int j = 0; j < 4; ++j)
                *(ushort8*)(&sVt[vd][vc0 + j * 8]) = *(const ushort8*)(vsrc + j * 8);
        }
        __syncthreads();

        floatx4 s[8];
        #pragma unroll
        for (int ni = 0; ni < 8; ++ni) s[ni] = (floatx4){0.f, 0.f, 0.f, 0.f};
        #pragma unroll
        for (int ks = 0; ks < 2; ++ks) {
            short8 aq = *(const short8*)(&sQ[w * 16 + lr][ks * 32 + lk]);
            #pragma unroll
            for (int ni = 0; ni < 8; ++ni) {
                short8 bk = *(const short8*)(&sK[ni * 16 + lr][ks * 32 + lk]);
                s[ni] = __builtin_amdgcn_mfma_f32_16x16x32_bf16(aq, bk, s[ni], 0, 0, 0);
            }
        }

        #pragma unroll
        for (int ni = 0; ni < 8; ++ni) {
            #pragma unroll
            for (int r = 0; r < 4; ++r) {
                const float p = __expf(s[ni][r] * tscale - m[r]) * invl[r];
                attnB[(long long)(w * 16 + lq + r) * 2048 + (k0 + ni * 16 + lr)] = p;
                sP[w * 16 + lq + r][ni * 16 + lr] = f2b(p);
            }
        }
        // sP rows are produced and consumed by the SAME wave; sVt covered by
        // the staging barrier -> no extra barrier needed here (lgkmcnt orders).

        #pragma unroll
        for (int kk = 0; kk < 4; ++kk) {
            short8 ap = *(const short8*)(&sP[w * 16 + lr][kk * 32 + lk]);
            #pragma unroll
            for (int nj = 0; nj < 4; ++nj) {
                short8 bv = *(const short8*)(&sVt[nj * 16 + lr][kk * 32 + lk]);
                o_acc[nj] = __builtin_amdgcn_mfma_f32_16x16x32_bf16(ap, bv, o_acc[nj], 0, 0, 0);
            }
        }
    }

    // ---- context epilogue: Cx[b, q, h, d] bf16 ----
    #pragma unroll
    for (int nj = 0; nj < 4; ++nj) {
        #pragma unroll
        for (int r = 0; r < 4; ++r) {
            const int row = w * 16 + lq + r;
            Cx[qkBase + (long long)(q0 + row) * 1024 + nj * 16 + lr] = f2b(o_acc[nj][r]);
        }
    }
}

// ---------------------------------------------------------------------------
// LayerNorm(proj(bf16) + resid(f32)) * gamma + beta -> f32. Rows of 1024.
// ---------------------------------------------------------------------------
__global__ __launch_bounds__(256) void ln_kernel(
    const ushort_t* __restrict__ proj, const float* __restrict__ resid,
    const float* __restrict__ gamma, const float* __restrict__ beta,
    float* __restrict__ out)
{
    const int row = blockIdx.x;
    const int t = threadIdx.x;
    const long long base = (long long)row * 1024 + t * 4;

    ushort4v vp = *(const ushort4v*)(proj + base);
    floatx4 vr = *(const floatx4*)(resid + base);
    float x[4];
    #pragma unroll
    for (int j = 0; j < 4; ++j) x[j] = b2f(vp[j]) + vr[j];

    __shared__ float red1[4], red2[4];
    float s = x[0] + x[1] + x[2] + x[3];
    #pragma unroll
    for (int o = 32; o > 0; o >>= 1) s += __shfl_xor(s, o, 64);
    if ((t & 63) == 0) red1[t >> 6] = s;
    __syncthreads();
    s = red1[0] + red1[1] + red1[2] + red1[3];
    const float mu = s * (1.0f / 1024.0f);

    float ss = 0.f;
    #pragma unroll
    for (int j = 0; j < 4; ++j) { const float d = x[j] - mu; ss += d * d; }
    #pragma unroll
    for (int o = 32; o > 0; o >>= 1) ss += __shfl_xor(ss, o, 64);
    if ((t & 63) == 0) red2[t >> 6] = ss;
    __syncthreads();
    ss = red2[0] + red2[1] + red2[2] + red2[3];
    const float rstd = rsqrtf(ss * (1.0f / 1024.0f) + 1e-5f);

    floatx4 g = *(const floatx4*)(gamma + t * 4);
    floatx4 b = *(const floatx4*)(beta + t * 4);
    floatx4 o;
    #pragma unroll
    for (int j = 0; j < 4; ++j)
        o[j] = (x[j] - mu) * rstd * g[j] + b[j];
    *(floatx4*)(out + base) = o;
}

// ---------------------------------------------------------------------------
extern "C" void kernel_launch(void* const* d_in, const int* in_sizes, int n_in,
                              void* d_out, int out_size, void* d_ws, size_t ws_size,
                              hipStream_t stream)
{
    const float* query = (const float*)d_in[0];
    const float* key_  = (const float*)d_in[1];
    const float* value = (const float*)d_in[2];
    const float* Wq = (const float*)d_in[3];
    const float* bq = (const float*)d_in[4];
    const float* Wk = (const float*)d_in[5];
    const float* bk = (const float*)d_in[6];
    const float* Wv = (const float*)d_in[7];
    const float* bv = (const float*)d_in[8];
    const float* Wo = (const float*)d_in[9];
    const float* bo = (const float*)d_in[10];
    const float* gamma = (const float*)d_in[11];
    const float* beta  = (const float*)d_in[12];
    const float* temp  = (const float*)d_in[13];

    float* out    = (float*)d_out;
    float* ln_out = out;                               // [2,2048,1024] f32
    float* attn   = out + (long long)4096 * 1024;      // [2,16,2048,2048] f32

    // ws (bf16 intermediates, 24 MB): Qb, Kb, Vt (transposed V)
    ushort_t* Qb = (ushort_t*)d_ws;
    ushort_t* Kb = Qb + 4194304;
    ushort_t* Vt = Kb + 4194304;                       // [2,16,64,2048]
    // context lives in the ln_out region of d_out until the output proj reads
    // it (ln_kernel overwrites it afterwards); Pj reuses Kb (K dead by then).
    ushort_t* Cx = (ushort_t*)out;
    ushort_t* Pj = Kb;

    const dim3 blk(256, 1, 1);

    // Q/K projections: [4096,1024] = in @ W^T + b   (f32 in -> bf16 out)
    gemm_nt_kernel<float, float, ushort_t, false><<<dim3(8, 32, 1), blk, 0, stream>>>(
        query, Wq, bq, Qb, 1024, 1024, 1024, 1024,
        1, 0LL, 0LL, 0LL, 0LL, 0LL, 0LL, nullptr);
    gemm_nt_kernel<float, float, ushort_t, false><<<dim3(8, 32, 1), blk, 0, stream>>>(
        key_, Wk, bk, Kb, 1024, 1024, 1024, 1024,
        1, 0LL, 0LL, 0LL, 0LL, 0LL, 0LL, nullptr);

    // V projection, TRANSPOSED: Vt[b, m=h*64+d, n=token] = Wv[m,:] . value[b,n,:] + bv[m]
    gemm_nt_kernel<float, float, ushort_t, true><<<dim3(16, 8, 2), blk, 0, stream>>>(
        Wv, value, bv, Vt, 1024, 1024, 1024, 2048,
        1, 0LL, 0LL, 2097152LL, 0LL, 2097152LL, 0LL, nullptr);

    // fused scores/softmax/attn-write/PV: grid (q-tiles=32, bh=32)
    fused_attn_kernel<<<dim3(32, 32, 1), blk, 0, stream>>>(
        Qb, Kb, Vt, attn, Cx, temp);

    // output projection: bf16 ctx x f32 Wo -> bf16 proj
    gemm_nt_kernel<ushort_t, float, ushort_t, false><<<dim3(8, 32, 1), blk, 0, stream>>>(
        Cx, Wo, bo, Pj, 1024, 1024, 1024, 1024,
        1, 0LL, 0LL, 0LL, 0LL, 0LL, 0LL, nullptr);

    // residual + layernorm -> f32
    ln_kernel<<<dim3(4096, 1, 1), blk, 0, stream>>>(Pj, query, gamma, beta, ln_out);
}